// Round 3
// baseline (385.194 us; speedup 1.0000x reference)
//
#include <hip/hip_runtime.h>
#include <math.h>

#define EMB_D 64
#define N_EMB_K 1024
#define HW 4096        // 64*64
#define CHW 262144     // 64*4096
#define NPTS 65536     // 16*64*64
#define Q_OFF 1
#define PERP_OFF 4194305
#define ENC_OFF 4194306
#define FRAG_OFF 4096   // floats: bf16-hi W fragments at ws+16KB (128 KB)

// ws layout (floats): [0..1023] c[k]=0.5||W_k||^2 ; [1024..2047] hist(uint) ;
// [2048] loss ; [4096..36863] bf16-hi B-frags (128 KB, chunk-lane order)

typedef __attribute__((ext_vector_type(8))) short short8;   // MFMA A/B frag (4 VGPRs)
typedef __attribute__((ext_vector_type(4))) float float4v;  // MFMA C/D frag
typedef __attribute__((ext_vector_type(4))) float f4;

union S8 { short8 v; unsigned short u[8]; };

__device__ __forceinline__ unsigned short f2bf_rne(float f) {
    unsigned u = __builtin_bit_cast(unsigned, f);
    unsigned r = u + 0x7FFFu + ((u >> 16) & 1u);
    return (unsigned short)(r >> 16);
}
__device__ __forceinline__ float bf2f(unsigned short h) {
    unsigned u = ((unsigned)h) << 16;
    return __builtin_bit_cast(float, u);
}

// 32 blocks x 256: c[k], hist/loss zero, bf16-hi frags.
// chunk = (code>>4)*2 + ks, lane = kg*16 + (code&15); element j <-> d = ks*32+kg*8+j
__global__ __launch_bounds__(256) void vq_prep(const float* __restrict__ W,
                                               float* __restrict__ ws) {
    const int gid = blockIdx.x * 256 + threadIdx.x;   // 0..8191
    {
        const int code = gid >> 3;
        const int seg  = gid & 7;           // ks = seg>>2, kg = seg&3
        const int d0   = seg << 3;
        const float4* wp = (const float4*)(W + (code << 6) + d0);
        const float4 g0 = wp[0], g1 = wp[1];
        const float vv[8] = {g0.x, g0.y, g0.z, g0.w, g1.x, g1.y, g1.z, g1.w};
        S8 hs;
        #pragma unroll
        for (int j = 0; j < 8; ++j) hs.u[j] = f2bf_rne(vv[j]);
        const int chunk = (code >> 4) * 2 + (seg >> 2);
        const int lane  = ((seg & 3) << 4) + (code & 15);
        ((short8*)(ws + FRAG_OFF))[chunk * 64 + lane] = hs.v;
    }
    if (gid < N_EMB_K) {
        const float* wk = W + (gid << 6);
        float s = 0.f;
        #pragma unroll
        for (int d = 0; d < EMB_D; ++d) s = fmaf(wk[d], wk[d], s);
        ws[gid] = 0.5f * s;
        ((unsigned int*)ws)[1024 + gid] = 0u;
        if (gid == 0) ws[2048] = 0.f;
    }
}

// 256 blocks x 1024 thr (16 waves), 1 block/CU (133 KB LDS) => 4 waves/SIMD.
// Block owns 256 points. k-loop is LDS+MFMA only (no global stores in loop).
// Epilogue: quant+loss+hist, and stash winner index as float into enc row[0].
__global__ __launch_bounds__(1024, 4) void vq_main(const float* __restrict__ in,
                                                   const float* __restrict__ W,
                                                   float* __restrict__ out,
                                                   float* __restrict__ ws) {
    __shared__ short8 frag_lds[8192];   // 128 KB: [chunk*64 + lane]
    __shared__ float  c_lds[1024];      // 4 KB
    __shared__ int    s_bk[256];

    const int tid  = threadIdx.x;
    const int lane = tid & 63;
    const int wv   = tid >> 6;          // 0..15
    const int n16  = lane & 15;
    const int quad = lane >> 4;

    const int blk = blockIdx.x;         // 0..255
    const int b   = blk >> 4;           // image (16 blocks per image)
    const int hw0 = (blk & 15) << 8;    // 256 consecutive hw positions

    // ---- stage frags + c into LDS ----
    {
        const short8* fsrc = (const short8*)(ws + FRAG_OFF);
        #pragma unroll
        for (int i = 0; i < 8; ++i) frag_lds[i * 1024 + tid] = fsrc[i * 1024 + tid];
        if (tid < 256) ((f4*)c_lds)[tid] = ((const f4*)ws)[tid];
    }

    // ---- x in registers + A-frags (x hi/lo): point p = wv*16+n16, d = quad*8+j (+32) ----
    float qx[16];
    short8 ah0, ah1, al0, al1;
    {
        const float* xp = in + (size_t)b * CHW + hw0 + (wv * 16 + n16);
        S8 h0, h1, l0, l1;
        #pragma unroll
        for (int j = 0; j < 8; ++j) {
            const int d = quad * 8 + j;
            const float v0 = __builtin_nontemporal_load(xp + d * HW);
            const float v1 = __builtin_nontemporal_load(xp + (d + 32) * HW);
            qx[j]     = v0;
            qx[j + 8] = v1;
            h0.u[j] = f2bf_rne(v0); l0.u[j] = f2bf_rne(v0 - bf2f(h0.u[j]));
            h1.u[j] = f2bf_rne(v1); l1.u[j] = f2bf_rne(v1 - bf2f(h1.u[j]));
        }
        ah0 = h0.v; al0 = l0.v; ah1 = h1.v; al1 = l1.v;
    }
    __syncthreads();   // frags/c visible

    float bestv[4] = {-3.0e38f, -3.0e38f, -3.0e38f, -3.0e38f};
    int   bestk[4] = {0, 0, 0, 0};

    // ---- k-loop: 64 tiles; per tile 2 ds_read_b128 + 1 ds_read + 4 MFMA ----
    #pragma unroll 2
    for (int t = 0; t < 64; ++t) {
        const short8 bh0 = frag_lds[(2 * t) * 64 + lane];
        const short8 bh1 = frag_lds[(2 * t + 1) * 64 + lane];
        const float  cv  = c_lds[(t << 4) + n16];
        float4v acc = {-cv, -cv, -cv, -cv};   // score = x.w - 0.5||w||^2
        acc = __builtin_amdgcn_mfma_f32_16x16x32_bf16(ah0, bh0, acc, 0, 0, 0);
        acc = __builtin_amdgcn_mfma_f32_16x16x32_bf16(ah1, bh1, acc, 0, 0, 0);
        acc = __builtin_amdgcn_mfma_f32_16x16x32_bf16(al0, bh0, acc, 0, 0, 0);
        acc = __builtin_amdgcn_mfma_f32_16x16x32_bf16(al1, bh1, acc, 0, 0, 0);
        const int code = (t << 4) + n16;
        #pragma unroll
        for (int r = 0; r < 4; ++r) {
            if (acc[r] > bestv[r]) { bestv[r] = acc[r]; bestk[r] = code; }  // strict > => lowest k
        }
    }

    // ---- reduce across the 16 code-lanes of each row group ----
    #pragma unroll
    for (int off = 1; off < 16; off <<= 1) {
        #pragma unroll
        for (int r = 0; r < 4; ++r) {
            const float ov = __shfl_xor(bestv[r], off, 64);
            const int   oi = __shfl_xor(bestk[r], off, 64);
            if (ov > bestv[r] || (ov == bestv[r] && oi < bestk[r])) {
                bestv[r] = ov; bestk[r] = oi;
            }
        }
    }
    if (n16 == 0) {
        #pragma unroll
        for (int r = 0; r < 4; ++r) s_bk[wv * 16 + quad * 4 + r] = bestk[r];
    }
    __syncthreads();   // publishes s_bk

    // ---- hist + stash winner index at row start of enc (vq_enc reads it) ----
    if (tid < 256) {
        const int bk = s_bk[tid];
        atomicAdd((unsigned int*)ws + 1024 + bk, 1u);
        out[ENC_OFF + (size_t)(blk * 256 + tid) * 1024] = (float)bk;
    }

    // ---- quant + loss from fp32 W winner row (L2-hot, exact vs reference) ----
    {
        const int p  = wv * 16 + n16;
        const int bk = s_bk[p];
        const float* wrow = W + (bk << 6) + quad * 8;
        union { f4 v[4]; float f[16]; } wq;
        wq.v[0] = *(const f4*)(wrow);
        wq.v[1] = *(const f4*)(wrow + 4);
        wq.v[2] = *(const f4*)(wrow + 32);
        wq.v[3] = *(const f4*)(wrow + 36);
        float* qbase = out + Q_OFF + (size_t)b * CHW + hw0 + p;
        float lsum = 0.f;
        #pragma unroll
        for (int j = 0; j < 8; ++j) {
            const int d = quad * 8 + j;
            const float q0 = wq.f[j];
            const float q1 = wq.f[j + 8];
            const float d0 = q0 - qx[j];
            const float d1 = q1 - qx[j + 8];
            lsum = fmaf(d0, d0, lsum);
            lsum = fmaf(d1, d1, lsum);
            qbase[d * HW]        = qx[j] + d0;       // straight-through arithmetic
            qbase[(d + 32) * HW] = qx[j + 8] + d1;
        }
        #pragma unroll
        for (int off = 1; off < 64; off <<= 1) lsum += __shfl_xor(lsum, off, 64);
        if (lane == 0) atomicAdd(ws + 2048, lsum);
    }
}

// Streaming one-hot writer: 2048 blocks x 256 (8192 waves), 8 rows/wave.
// Lane 0 reads the stashed index from row[0], broadcast, then the wave writes
// the full 4 KB row with plain coalesced dwordx4 stores (fill-kernel pattern).
__global__ __launch_bounds__(256) void vq_enc(float* __restrict__ out) {
    const int tid  = threadIdx.x;
    const int lane = tid & 63;
    const int wv   = tid >> 6;
    const int gw   = blockIdx.x * 4 + wv;     // 0..8191
    float* rows = out + ENC_OFF + (size_t)gw * 8 * 1024;

    float idxf[8];
    if (lane == 0) {
        #pragma unroll
        for (int r = 0; r < 8; ++r) idxf[r] = rows[(size_t)r * 1024];
    }
    #pragma unroll
    for (int r = 0; r < 8; ++r) {
        const int bk = __shfl((int)idxf[r], 0, 64);
        float* row = rows + (size_t)r * 1024;
        #pragma unroll
        for (int pass = 0; pass < 4; ++pass) {
            const int base = (pass * 64 + lane) * 4;   // float index in row
            f4 v;
            v.x = (base + 0 == bk) ? 1.0f : 0.0f;
            v.y = (base + 1 == bk) ? 1.0f : 0.0f;
            v.z = (base + 2 == bk) ? 1.0f : 0.0f;
            v.w = (base + 3 == bk) ? 1.0f : 0.0f;
            *(f4*)(row + base) = v;
        }
    }
}

__global__ __launch_bounds__(256) void vq_final(const float* __restrict__ ws,
                                                float* __restrict__ out) {
    __shared__ float red[256];
    const int tid = threadIdx.x;
    const unsigned int* hist = (const unsigned int*)ws + 1024;
    float local = 0.f;
    #pragma unroll
    for (int j = 0; j < 4; ++j) {
        const unsigned int cnt = hist[tid + j * 256];
        const float pr = (float)cnt * (1.0f / 65536.0f);
        local += pr * logf(pr + 1e-10f);
    }
    red[tid] = local;
    __syncthreads();
    for (int off = 128; off > 0; off >>= 1) {
        if (tid < off) red[tid] += red[tid + off];
        __syncthreads();
    }
    if (tid == 0) {
        out[PERP_OFF] = expf(-red[0]);
        out[0] = 1.25f * ws[2048] * (1.0f / 4194304.0f);
    }
}

extern "C" void kernel_launch(void* const* d_in, const int* in_sizes, int n_in,
                              void* d_out, int out_size, void* d_ws, size_t ws_size,
                              hipStream_t stream) {
    const float* in = (const float*)d_in[0];   // (16,64,64,64) fp32 NCHW
    const float* W  = (const float*)d_in[1];   // (1024,64) fp32
    float* out = (float*)d_out;                // [loss | quant(4194304) | perp | enc(67108864)]
    float* ws  = (float*)d_ws;

    vq_prep<<<32, 256, 0, stream>>>(W, ws);
    vq_main<<<NPTS / 256, 1024, 0, stream>>>(in, W, out, ws);
    vq_enc<<<2048, 256, 0, stream>>>(out);
    vq_final<<<1, 256, 0, stream>>>(ws, out);
}

// Round 5
// 384.602 us; speedup vs baseline: 1.0015x; 1.0015x over previous
//
#include <hip/hip_runtime.h>
#include <math.h>

#define EMB_D 64
#define N_EMB_K 1024
#define HW 4096        // 64*64
#define CHW 262144     // 64*4096
#define NPTS 65536     // 16*64*64
#define Q_OFF 1
#define PERP_OFF 4194305
#define ENC_OFF 4194306
#define FRAG_OFF 4096   // floats: bf16-hi W fragments at ws+16KB (128 KB)

// ws layout (floats): [0..1023] c[k]=0.5||W_k||^2 ; [1024..2047] hist(uint) ;
// [2048] loss ; [4096..36863] bf16-hi B-frags (128 KB, chunk-lane order)

typedef __attribute__((ext_vector_type(8))) short short8;   // MFMA A/B frag (4 VGPRs)
typedef __attribute__((ext_vector_type(4))) float float4v;  // MFMA C/D frag
typedef __attribute__((ext_vector_type(2))) float f2;
typedef __attribute__((ext_vector_type(4))) float f4;

union S8 { short8 v; unsigned short u[8]; };

__device__ __forceinline__ unsigned short f2bf_rne(float f) {
    unsigned u = __builtin_bit_cast(unsigned, f);
    unsigned r = u + 0x7FFFu + ((u >> 16) & 1u);
    return (unsigned short)(r >> 16);
}
__device__ __forceinline__ float bf2f(unsigned short h) {
    unsigned u = ((unsigned)h) << 16;
    return __builtin_bit_cast(float, u);
}

// 32 blocks x 256: c[k], hist/loss zero, bf16-hi frags.
// chunk = (code>>4)*2 + ks, lane = kg*16 + (code&15); element j <-> d = ks*32+kg*8+j
__global__ __launch_bounds__(256) void vq_prep(const float* __restrict__ W,
                                               float* __restrict__ ws) {
    const int gid = blockIdx.x * 256 + threadIdx.x;   // 0..8191
    {
        const int code = gid >> 3;
        const int seg  = gid & 7;           // ks = seg>>2, kg = seg&3
        const int d0   = seg << 3;
        const float4* wp = (const float4*)(W + (code << 6) + d0);
        const float4 g0 = wp[0], g1 = wp[1];
        const float vv[8] = {g0.x, g0.y, g0.z, g0.w, g1.x, g1.y, g1.z, g1.w};
        S8 hs;
        #pragma unroll
        for (int j = 0; j < 8; ++j) hs.u[j] = f2bf_rne(vv[j]);
        const int chunk = (code >> 4) * 2 + (seg >> 2);
        const int lane  = ((seg & 3) << 4) + (code & 15);
        ((short8*)(ws + FRAG_OFF))[chunk * 64 + lane] = hs.v;
    }
    if (gid < N_EMB_K) {
        const float* wk = W + (gid << 6);
        float s = 0.f;
        #pragma unroll
        for (int d = 0; d < EMB_D; ++d) s = fmaf(wk[d], wk[d], s);
        ws[gid] = 0.5f * s;
        ((unsigned int*)ws)[1024 + gid] = 0u;
        if (gid == 0) ws[2048] = 0.f;
    }
}

// Fill-clone: zero the whole enc region (268 MB) with perfectly aligned
// dwordx4 grid-stride stores. 2048 blocks x 256 thr = 8 waves/SIMD.
// Region starts at float-offset ENC_OFF (== 2 mod 4): 2-float prologue,
// 16777215 aligned f4, 2-float epilogue.
__global__ __launch_bounds__(256) void vq_zero(float* __restrict__ out) {
    const int gid = blockIdx.x * 256 + threadIdx.x;   // 0..524287
    f4* base = (f4*)(out + ENC_OFF + 2);              // 16B-aligned
    const f4 z4 = {0.f, 0.f, 0.f, 0.f};
    #pragma unroll
    for (int it = 0; it < 31; ++it) base[it * 524288 + gid] = z4;
    const int i = 31 * 524288 + gid;
    if (i < 16777215) base[i] = z4;
    if (gid == 0) {
        const f2 z2 = {0.f, 0.f};
        *(f2*)(out + ENC_OFF) = z2;                   // floats 0,1 (8B-aligned)
        *(f2*)(out + ENC_OFF + 67108862) = z2;        // last two floats
    }
}

// R0 structure, zeroing removed: 1024 blocks x 256 thr, 1 block/CU (133 KB LDS).
// Block owns 64 points. k-loop is pure LDS+MFMA; epilogue writes quant (16 KB),
// the one-hot ones (zeros pre-written by vq_zero), hist, loss.
__global__ __launch_bounds__(256, 1) void vq_main(const float* __restrict__ in,
                                                  const float* __restrict__ W,
                                                  float* __restrict__ out,
                                                  float* __restrict__ ws) {
    __shared__ short8 frag_lds[8192];   // 128 KB: [chunk*64 + lane]
    __shared__ float  c_lds[1024];      // 4 KB
    __shared__ int    s_bk[64];

    const int tid  = threadIdx.x;
    const int lane = tid & 63;
    const int wv   = tid >> 6;
    const int n16  = lane & 15;
    const int quad = lane >> 4;

    const int blk = blockIdx.x;
    const int b   = blk >> 6;              // image (64 blocks per image)
    const int hw0 = (blk & 63) * 64;       // 64 consecutive hw positions

    // ---- stage frags + c into LDS ----
    {
        const short8* fsrc = (const short8*)(ws + FRAG_OFF);
        #pragma unroll
        for (int i = 0; i < 32; ++i) frag_lds[i * 256 + tid] = fsrc[i * 256 + tid];
        ((f4*)c_lds)[tid] = ((const f4*)ws)[tid];
    }

    // ---- x in registers + A-frags (x hi/lo): point p = wv*16+n16, d = quad*8+j (+32) ----
    float qx[16];
    short8 ah0, ah1, al0, al1;
    {
        const float* xp = in + (size_t)b * CHW + hw0 + (wv * 16 + n16);
        S8 h0, h1, l0, l1;
        #pragma unroll
        for (int j = 0; j < 8; ++j) {
            const int d = quad * 8 + j;
            const float v0 = xp[d * HW];
            const float v1 = xp[(d + 32) * HW];
            qx[j]     = v0;
            qx[j + 8] = v1;
            h0.u[j] = f2bf_rne(v0); l0.u[j] = f2bf_rne(v0 - bf2f(h0.u[j]));
            h1.u[j] = f2bf_rne(v1); l1.u[j] = f2bf_rne(v1 - bf2f(h1.u[j]));
        }
        ah0 = h0.v; al0 = l0.v; ah1 = h1.v; al1 = l1.v;
    }
    __syncthreads();   // frags/c visible

    float bestv[4] = {-3.0e38f, -3.0e38f, -3.0e38f, -3.0e38f};
    int   bestk[4] = {0, 0, 0, 0};
    float* encrow0 = out + ENC_OFF + (size_t)blk * 65536;   // block's 64 rows

    // ---- k-loop: 64 tiles; per tile 2 ds_read_b128 + 1 ds_read + 4 MFMA ----
    #pragma unroll 2
    for (int t = 0; t < 64; ++t) {
        const short8 bh0 = frag_lds[(2 * t) * 64 + lane];
        const short8 bh1 = frag_lds[(2 * t + 1) * 64 + lane];
        const float  cv  = c_lds[(t << 4) + n16];
        float4v acc = {-cv, -cv, -cv, -cv};   // score = x.w - 0.5||w||^2
        acc = __builtin_amdgcn_mfma_f32_16x16x32_bf16(ah0, bh0, acc, 0, 0, 0);
        acc = __builtin_amdgcn_mfma_f32_16x16x32_bf16(ah1, bh1, acc, 0, 0, 0);
        acc = __builtin_amdgcn_mfma_f32_16x16x32_bf16(al0, bh0, acc, 0, 0, 0);
        acc = __builtin_amdgcn_mfma_f32_16x16x32_bf16(al1, bh1, acc, 0, 0, 0);
        const int code = (t << 4) + n16;
        #pragma unroll
        for (int r = 0; r < 4; ++r) {
            if (acc[r] > bestv[r]) { bestv[r] = acc[r]; bestk[r] = code; }  // strict > => lowest k
        }
    }

    // ---- reduce across the 16 code-lanes of each row group ----
    #pragma unroll
    for (int off = 1; off < 16; off <<= 1) {
        #pragma unroll
        for (int r = 0; r < 4; ++r) {
            const float ov = __shfl_xor(bestv[r], off, 64);
            const int   oi = __shfl_xor(bestk[r], off, 64);
            if (ov > bestv[r] || (ov == bestv[r] && oi < bestk[r])) {
                bestv[r] = ov; bestk[r] = oi;
            }
        }
    }
    if (n16 == 0) {
        #pragma unroll
        for (int r = 0; r < 4; ++r) s_bk[wv * 16 + quad * 4 + r] = bestk[r];
    }
    __syncthreads();   // publishes s_bk

    // ---- ones + histogram (zeros already written by vq_zero, stream-ordered) ----
    if (tid < 64) {
        const int bk = s_bk[tid];
        atomicAdd((unsigned int*)ws + 1024 + bk, 1u);
        encrow0[(size_t)tid * 1024 + bk] = 1.0f;
    }

    // ---- quant + loss from LDS bf16 winner row (no global loads) ----
    {
        const int p  = wv * 16 + n16;
        const int bk = s_bk[p];
        const int ch = (bk >> 4) * 2;
        const int fl = quad * 16 + (bk & 15);
        const S8 w0 = {frag_lds[ch * 64 + fl]};
        const S8 w1 = {frag_lds[(ch + 1) * 64 + fl]};
        float* qbase = out + Q_OFF + (size_t)b * CHW + hw0 + p;
        float lsum = 0.f;
        #pragma unroll
        for (int j = 0; j < 8; ++j) {
            const int d = quad * 8 + j;
            const float q0 = bf2f(w0.u[j]);
            const float q1 = bf2f(w1.u[j]);
            const float d0 = q0 - qx[j];
            const float d1 = q1 - qx[j + 8];
            lsum = fmaf(d0, d0, lsum);
            lsum = fmaf(d1, d1, lsum);
            qbase[d * HW]        = qx[j] + d0;       // straight-through arithmetic
            qbase[(d + 32) * HW] = qx[j + 8] + d1;
        }
        #pragma unroll
        for (int off = 1; off < 64; off <<= 1) lsum += __shfl_xor(lsum, off, 64);
        if (lane == 0) atomicAdd(ws + 2048, lsum);
    }
}

__global__ __launch_bounds__(256) void vq_final(const float* __restrict__ ws,
                                                float* __restrict__ out) {
    __shared__ float red[256];
    const int tid = threadIdx.x;
    const unsigned int* hist = (const unsigned int*)ws + 1024;
    float local = 0.f;
    #pragma unroll
    for (int j = 0; j < 4; ++j) {
        const unsigned int cnt = hist[tid + j * 256];
        const float pr = (float)cnt * (1.0f / 65536.0f);
        local += pr * logf(pr + 1e-10f);
    }
    red[tid] = local;
    __syncthreads();
    for (int off = 128; off > 0; off >>= 1) {
        if (tid < off) red[tid] += red[tid + off];
        __syncthreads();
    }
    if (tid == 0) {
        out[PERP_OFF] = expf(-red[0]);
        out[0] = 1.25f * ws[2048] * (1.0f / 4194304.0f);
    }
}

extern "C" void kernel_launch(void* const* d_in, const int* in_sizes, int n_in,
                              void* d_out, int out_size, void* d_ws, size_t ws_size,
                              hipStream_t stream) {
    const float* in = (const float*)d_in[0];   // (16,64,64,64) fp32 NCHW
    const float* W  = (const float*)d_in[1];   // (1024,64) fp32
    float* out = (float*)d_out;                // [loss | quant(4194304) | perp | enc(67108864)]
    float* ws  = (float*)d_ws;

    vq_prep<<<32, 256, 0, stream>>>(W, ws);
    vq_zero<<<2048, 256, 0, stream>>>(out);
    vq_main<<<NPTS / 64, 256, 0, stream>>>(in, W, out, ws);
    vq_final<<<1, 256, 0, stream>>>(ws, out);
}

// Round 6
// 367.639 us; speedup vs baseline: 1.0477x; 1.0461x over previous
//
#include <hip/hip_runtime.h>
#include <math.h>

#define EMB_D 64
#define N_EMB_K 1024
#define HW 4096        // 64*64
#define CHW 262144     // 64*4096
#define NPTS 65536     // 16*64*64
#define Q_OFF 1
#define PERP_OFF 4194305
#define ENC_OFF 4194306
#define FRAG_OFF 4096   // floats: bf16-hi W fragments at ws+16KB (128 KB)

// ws layout (floats): [0..1023] c[k]=0.5||W_k||^2 ; [1024..2047] hist(uint) ;
// [2048] loss ; [4096..36863] bf16-hi B-frags (128 KB, chunk-lane order)

typedef __attribute__((ext_vector_type(8))) short short8;   // MFMA A/B frag (4 VGPRs)
typedef __attribute__((ext_vector_type(4))) float float4v;  // MFMA C/D frag
typedef __attribute__((ext_vector_type(2))) float f2;
typedef __attribute__((ext_vector_type(4))) float f4;

union S8 { short8 v; unsigned short u[8]; };

__device__ __forceinline__ unsigned short f2bf_rne(float f) {
    unsigned u = __builtin_bit_cast(unsigned, f);
    unsigned r = u + 0x7FFFu + ((u >> 16) & 1u);
    return (unsigned short)(r >> 16);
}
__device__ __forceinline__ float bf2f(unsigned short h) {
    unsigned u = ((unsigned)h) << 16;
    return __builtin_bit_cast(float, u);
}

// 32 blocks x 256: c[k], hist/loss zero, bf16-hi frags.
// chunk = (code>>4)*2 + ks, lane = kg*16 + (code&15); element j <-> d = ks*32+kg*8+j
__global__ __launch_bounds__(256) void vq_prep(const float* __restrict__ W,
                                               float* __restrict__ ws) {
    const int gid = blockIdx.x * 256 + threadIdx.x;   // 0..8191
    {
        const int code = gid >> 3;
        const int seg  = gid & 7;           // ks = seg>>2, kg = seg&3
        const int d0   = seg << 3;
        const float4* wp = (const float4*)(W + (code << 6) + d0);
        const float4 g0 = wp[0], g1 = wp[1];
        const float vv[8] = {g0.x, g0.y, g0.z, g0.w, g1.x, g1.y, g1.z, g1.w};
        S8 hs;
        #pragma unroll
        for (int j = 0; j < 8; ++j) hs.u[j] = f2bf_rne(vv[j]);
        const int chunk = (code >> 4) * 2 + (seg >> 2);
        const int lane  = ((seg & 3) << 4) + (code & 15);
        ((short8*)(ws + FRAG_OFF))[chunk * 64 + lane] = hs.v;
    }
    if (gid < N_EMB_K) {
        const float* wk = W + (gid << 6);
        float s = 0.f;
        #pragma unroll
        for (int d = 0; d < EMB_D; ++d) s = fmaf(wk[d], wk[d], s);
        ws[gid] = 0.5f * s;
        ((unsigned int*)ws)[1024 + gid] = 0u;
        if (gid == 0) ws[2048] = 0.f;
    }
}

// 256 blocks x 1024 thr (16 waves), 1 block/CU (133 KB LDS) => 4 waves/SIMD.
// Block owns 256 points; ONE generation per CU (no re-stage, no re-paid latency).
// k-loop: LDS-only loads + MFMA + interleaved PLAIN enc-zero stores (fire-and-
// forget; drain overlaps compute/loop, ordered by the single end barrier).
__global__ __launch_bounds__(1024, 4) void vq_main(const float* __restrict__ in,
                                                   const float* __restrict__ W,
                                                   float* __restrict__ out,
                                                   float* __restrict__ ws) {
    __shared__ short8 frag_lds[8192];   // 128 KB: [chunk*64 + lane]
    __shared__ float  c_lds[1024];      // 4 KB
    __shared__ int    s_bk[256];

    const int tid  = threadIdx.x;
    const int lane = tid & 63;
    const int wv   = tid >> 6;          // 0..15
    const int n16  = lane & 15;
    const int quad = lane >> 4;

    const int blk = blockIdx.x;         // 0..255
    const int b   = blk >> 4;           // image (16 blocks per image)
    const int hw0 = (blk & 15) << 8;    // 256 consecutive hw positions

    // ---- stage frags + c into LDS (plain loads; no stores in flight yet) ----
    {
        const short8* fsrc = (const short8*)(ws + FRAG_OFF);
        #pragma unroll
        for (int i = 0; i < 8; ++i) frag_lds[i * 1024 + tid] = fsrc[i * 1024 + tid];
        if (tid < 256) ((f4*)c_lds)[tid] = ((const f4*)ws)[tid];
    }

    // ---- x in registers + A-frags (x hi/lo): point p = wv*16+n16, d = quad*8+j (+32) ----
    float qx[16];
    short8 ah0, ah1, al0, al1;
    {
        const float* xp = in + (size_t)b * CHW + hw0 + (wv * 16 + n16);
        S8 h0, h1, l0, l1;
        #pragma unroll
        for (int j = 0; j < 8; ++j) {
            const int d = quad * 8 + j;
            const float v0 = __builtin_nontemporal_load(xp + d * HW);
            const float v1 = __builtin_nontemporal_load(xp + (d + 32) * HW);
            qx[j]     = v0;
            qx[j + 8] = v1;
            h0.u[j] = f2bf_rne(v0); l0.u[j] = f2bf_rne(v0 - bf2f(h0.u[j]));
            h1.u[j] = f2bf_rne(v1); l1.u[j] = f2bf_rne(v1 - bf2f(h1.u[j]));
        }
        ah0 = h0.v; al0 = l0.v; ah1 = h1.v; al1 = l1.v;
    }
    __syncthreads();   // frags/c visible; all x loads consumed before any store

    float bestv[4] = {-3.0e38f, -3.0e38f, -3.0e38f, -3.0e38f};
    int   bestk[4] = {0, 0, 0, 0};
    float* encrow0 = out + ENC_OFF + (size_t)blk * 262144;   // block's 256 rows
    const f4 z4 = {0.f, 0.f, 0.f, 0.f};
    const f2 z2 = {0.f, 0.f};
    const int rgrp = tid >> 8;      // 0..3: which of the tile's 4 rows
    const int sub  = tid & 255;

    // ---- k-loop: 64 tiles; per tile 2 ds_read_b128 + 1 ds_read + 4 MFMA
    //      + one enc-zero PLAIN store (tile t <-> rows 4t..4t+3), never waited ----
    #pragma unroll 2
    for (int t = 0; t < 64; ++t) {
        const short8 bh0 = frag_lds[(2 * t) * 64 + lane];
        const short8 bh1 = frag_lds[(2 * t + 1) * 64 + lane];
        const float  cv  = c_lds[(t << 4) + n16];
        {   // zero row 4t+rgrp: interior 255 f4 (16B-aligned at +2 floats) + edges
            float* row = encrow0 + (4 * t + rgrp) * 1024;
            if (sub < 255) {
                *(f4*)(row + 2 + 4 * sub) = z4;
            } else {
                *(f2*)(row)        = z2;
                *(f2*)(row + 1022) = z2;
            }
        }
        float4v acc = {-cv, -cv, -cv, -cv};   // score = x.w - 0.5||w||^2
        acc = __builtin_amdgcn_mfma_f32_16x16x32_bf16(ah0, bh0, acc, 0, 0, 0);
        acc = __builtin_amdgcn_mfma_f32_16x16x32_bf16(ah1, bh1, acc, 0, 0, 0);
        acc = __builtin_amdgcn_mfma_f32_16x16x32_bf16(al0, bh0, acc, 0, 0, 0);
        acc = __builtin_amdgcn_mfma_f32_16x16x32_bf16(al1, bh1, acc, 0, 0, 0);
        const int code = (t << 4) + n16;
        #pragma unroll
        for (int r = 0; r < 4; ++r) {
            if (acc[r] > bestv[r]) { bestv[r] = acc[r]; bestk[r] = code; }  // strict > => lowest k
        }
    }

    // ---- reduce across the 16 code-lanes of each row group ----
    #pragma unroll
    for (int off = 1; off < 16; off <<= 1) {
        #pragma unroll
        for (int r = 0; r < 4; ++r) {
            const float ov = __shfl_xor(bestv[r], off, 64);
            const int   oi = __shfl_xor(bestk[r], off, 64);
            if (ov > bestv[r] || (ov == bestv[r] && oi < bestk[r])) {
                bestv[r] = ov; bestk[r] = oi;
            }
        }
    }
    if (n16 == 0) {
        #pragma unroll
        for (int r = 0; r < 4; ++r) s_bk[wv * 16 + quad * 4 + r] = bestk[r];
    }
    __syncthreads();   // publishes s_bk AND drains the (mostly-retired) zero stores

    // ---- ones + histogram (ordered after zeros by the barrier) ----
    if (tid < 256) {
        const int bk = s_bk[tid];
        atomicAdd((unsigned int*)ws + 1024 + bk, 1u);
        encrow0[(size_t)tid * 1024 + bk] = 1.0f;
    }

    // ---- quant + loss from fp32 W winner row (L2-hot, exact vs reference) ----
    {
        const int p  = wv * 16 + n16;
        const int bk = s_bk[p];
        const float* wrow = W + (bk << 6) + quad * 8;
        union { f4 v[4]; float f[16]; } wq;
        wq.v[0] = *(const f4*)(wrow);
        wq.v[1] = *(const f4*)(wrow + 4);
        wq.v[2] = *(const f4*)(wrow + 32);
        wq.v[3] = *(const f4*)(wrow + 36);
        float* qbase = out + Q_OFF + (size_t)b * CHW + hw0 + p;
        float lsum = 0.f;
        #pragma unroll
        for (int j = 0; j < 8; ++j) {
            const int d = quad * 8 + j;
            const float q0 = wq.f[j];
            const float q1 = wq.f[j + 8];
            const float d0 = q0 - qx[j];
            const float d1 = q1 - qx[j + 8];
            lsum = fmaf(d0, d0, lsum);
            lsum = fmaf(d1, d1, lsum);
            qbase[d * HW]        = qx[j] + d0;       // straight-through arithmetic
            qbase[(d + 32) * HW] = qx[j + 8] + d1;
        }
        #pragma unroll
        for (int off = 1; off < 64; off <<= 1) lsum += __shfl_xor(lsum, off, 64);
        if (lane == 0) atomicAdd(ws + 2048, lsum);
    }
}

__global__ __launch_bounds__(256) void vq_final(const float* __restrict__ ws,
                                                float* __restrict__ out) {
    __shared__ float red[256];
    const int tid = threadIdx.x;
    const unsigned int* hist = (const unsigned int*)ws + 1024;
    float local = 0.f;
    #pragma unroll
    for (int j = 0; j < 4; ++j) {
        const unsigned int cnt = hist[tid + j * 256];
        const float pr = (float)cnt * (1.0f / 65536.0f);
        local += pr * logf(pr + 1e-10f);
    }
    red[tid] = local;
    __syncthreads();
    for (int off = 128; off > 0; off >>= 1) {
        if (tid < off) red[tid] += red[tid + off];
        __syncthreads();
    }
    if (tid == 0) {
        out[PERP_OFF] = expf(-red[0]);
        out[0] = 1.25f * ws[2048] * (1.0f / 4194304.0f);
    }
}

extern "C" void kernel_launch(void* const* d_in, const int* in_sizes, int n_in,
                              void* d_out, int out_size, void* d_ws, size_t ws_size,
                              hipStream_t stream) {
    const float* in = (const float*)d_in[0];   // (16,64,64,64) fp32 NCHW
    const float* W  = (const float*)d_in[1];   // (1024,64) fp32
    float* out = (float*)d_out;                // [loss | quant(4194304) | perp | enc(67108864)]
    float* ws  = (float*)d_ws;

    vq_prep<<<32, 256, 0, stream>>>(W, ws);
    vq_main<<<NPTS / 256, 1024, 0, stream>>>(in, W, out, ws);
    vq_final<<<1, 256, 0, stream>>>(ws, out);
}

// Round 14
// 317.607 us; speedup vs baseline: 1.2128x; 1.1575x over previous
//
#include <hip/hip_runtime.h>
#include <math.h>

#define EMB_D 64
#define N_EMB_K 1024
#define HW 4096        // 64*64
#define CHW 262144     // 64*4096
#define NPTS 65536     // 16*64*64
#define Q_OFF 1
#define PERP_OFF 4194305
#define ENC_OFF 4194306
#define FRAG_OFF 4096   // floats: bf16-hi W fragments at ws+16KB (128 KB)

// ws layout (floats): [0..1023] c[k]=0.5||W_k||^2 ; [1024..2047] hist(uint) ;
// [2048] loss ; [4096..36863] bf16-hi B-frags (128 KB, chunk-lane order)

typedef __attribute__((ext_vector_type(8))) short short8;   // MFMA A/B frag (4 VGPRs)
typedef __attribute__((ext_vector_type(4))) float float4v;  // MFMA C/D frag
typedef __attribute__((ext_vector_type(2))) float f2;
typedef __attribute__((ext_vector_type(4))) float f4;

union S8 { short8 v; unsigned short u[8]; };

__device__ __forceinline__ unsigned short f2bf_rne(float f) {
    unsigned u = __builtin_bit_cast(unsigned, f);
    unsigned r = u + 0x7FFFu + ((u >> 16) & 1u);
    return (unsigned short)(r >> 16);
}
__device__ __forceinline__ float bf2f(unsigned short h) {
    unsigned u = ((unsigned)h) << 16;
    return __builtin_bit_cast(float, u);
}

// 32 blocks x 256: c[k], hist/loss zero, bf16-hi frags.
// chunk = (code>>4)*2 + ks, lane = kg*16 + (code&15); element j <-> d = ks*32+kg*8+j
__global__ __launch_bounds__(256) void vq_prep(const float* __restrict__ W,
                                               float* __restrict__ ws) {
    const int gid = blockIdx.x * 256 + threadIdx.x;   // 0..8191
    {
        const int code = gid >> 3;
        const int seg  = gid & 7;           // ks = seg>>2, kg = seg&3
        const int d0   = seg << 3;
        const float4* wp = (const float4*)(W + (code << 6) + d0);
        const float4 g0 = wp[0], g1 = wp[1];
        const float vv[8] = {g0.x, g0.y, g0.z, g0.w, g1.x, g1.y, g1.z, g1.w};
        S8 hs;
        #pragma unroll
        for (int j = 0; j < 8; ++j) hs.u[j] = f2bf_rne(vv[j]);
        const int chunk = (code >> 4) * 2 + (seg >> 2);
        const int lane  = ((seg & 3) << 4) + (code & 15);
        ((short8*)(ws + FRAG_OFF))[chunk * 64 + lane] = hs.v;
    }
    if (gid < N_EMB_K) {
        const float* wk = W + (gid << 6);
        float s = 0.f;
        #pragma unroll
        for (int d = 0; d < EMB_D; ++d) s = fmaf(wk[d], wk[d], s);
        ws[gid] = 0.5f * s;
        ((unsigned int*)ws)[1024 + gid] = 0u;
        if (gid == 0) ws[2048] = 0.f;
    }
}

// 256 blocks x 256 thr, 1 block/CU (133 KB LDS), ONE generation.
// Block owns 256 points = 4 point-groups per wave: per k-tile one pair of
// ds_read_b128 feeds 16 MFMAs (4 independent chains) -> ILP covers latency
// at 1 wave/SIMD. Enc-zero stores interleaved (wave w zeros row 4t+w),
// fire-and-forget until the single end barrier.
__global__ __launch_bounds__(256, 1) void vq_main(const float* __restrict__ in,
                                                  const float* __restrict__ W,
                                                  float* __restrict__ out,
                                                  float* __restrict__ ws) {
    __shared__ short8 frag_lds[8192];   // 128 KB: [chunk*64 + lane]
    __shared__ float  c_lds[1024];      // 4 KB
    __shared__ int    s_bk[256];

    const int tid  = threadIdx.x;
    const int lane = tid & 63;
    const int wv   = tid >> 6;          // 0..3
    const int n16  = lane & 15;
    const int quad = lane >> 4;

    const int blk = blockIdx.x;         // 0..255
    const int b   = blk >> 4;           // image (16 blocks per image)
    const int hw0 = (blk & 15) << 8;    // 256 consecutive hw positions

    // ---- stage frags + c into LDS ----
    {
        const short8* fsrc = (const short8*)(ws + FRAG_OFF);
        #pragma unroll
        for (int i = 0; i < 32; ++i) frag_lds[i * 256 + tid] = fsrc[i * 256 + tid];
        ((f4*)c_lds)[tid] = ((const f4*)ws)[tid];
    }

    // ---- x in registers + A-frags for 4 groups: group g points = wv*64+g*16+n16,
    //      dims quad*8+j (+32) ----
    float qx[4][16];
    short8 ah0[4], ah1[4], al0[4], al1[4];
    #pragma unroll
    for (int g = 0; g < 4; ++g) {
        const float* xp = in + (size_t)b * CHW + hw0 + (wv * 64 + g * 16 + n16);
        S8 h0, h1, l0, l1;
        #pragma unroll
        for (int j = 0; j < 8; ++j) {
            const int d = quad * 8 + j;
            const float v0 = xp[d * HW];
            const float v1 = xp[(d + 32) * HW];
            qx[g][j]     = v0;
            qx[g][j + 8] = v1;
            h0.u[j] = f2bf_rne(v0); l0.u[j] = f2bf_rne(v0 - bf2f(h0.u[j]));
            h1.u[j] = f2bf_rne(v1); l1.u[j] = f2bf_rne(v1 - bf2f(h1.u[j]));
        }
        ah0[g] = h0.v; al0[g] = l0.v; ah1[g] = h1.v; al1[g] = l1.v;
    }
    __syncthreads();   // frags/c visible; x consumed before any store issues

    float bestv[4][4];
    int   bestk[4][4];
    #pragma unroll
    for (int g = 0; g < 4; ++g)
        #pragma unroll
        for (int r = 0; r < 4; ++r) { bestv[g][r] = -3.0e38f; bestk[g][r] = 0; }

    float* encrow0 = out + ENC_OFF + (size_t)blk * 262144;   // block's 256 rows
    const f4 z4 = {0.f, 0.f, 0.f, 0.f};
    const f2 z2 = {0.f, 0.f};

    // ---- k-loop: 64 tiles; per tile 2 ds_read_b128 + 1 ds_read + 16 MFMA
    //      (4 indep chains) + 4 coalesced f4 zero-stores (row 4t+wv), unwaited ----
    #pragma unroll 2
    for (int t = 0; t < 64; ++t) {
        const short8 bh0 = frag_lds[(2 * t) * 64 + lane];
        const short8 bh1 = frag_lds[(2 * t + 1) * 64 + lane];
        const float  cv  = c_lds[(t << 4) + n16];
        {   // wave wv zeros row 4t+wv: interior 255 f4 (aligned at +2) + edges
            float* row = encrow0 + (4 * t + wv) * 1024;
            #pragma unroll
            for (int i = 0; i < 4; ++i) {
                const int s = i * 64 + lane;
                if (s < 255) {
                    ((f4*)(row + 2))[s] = z4;
                } else {   // lane 63, i==3: the two f2 edges
                    *(f2*)(row)        = z2;
                    *(f2*)(row + 1022) = z2;
                }
            }
        }
        const int code = (t << 4) + n16;
        #pragma unroll
        for (int g = 0; g < 4; ++g) {
            float4v acc = {-cv, -cv, -cv, -cv};   // score = x.w - 0.5||w||^2
            acc = __builtin_amdgcn_mfma_f32_16x16x32_bf16(ah0[g], bh0, acc, 0, 0, 0);
            acc = __builtin_amdgcn_mfma_f32_16x16x32_bf16(ah1[g], bh1, acc, 0, 0, 0);
            acc = __builtin_amdgcn_mfma_f32_16x16x32_bf16(al0[g], bh0, acc, 0, 0, 0);
            acc = __builtin_amdgcn_mfma_f32_16x16x32_bf16(al1[g], bh1, acc, 0, 0, 0);
            #pragma unroll
            for (int r = 0; r < 4; ++r) {
                if (acc[r] > bestv[g][r]) { bestv[g][r] = acc[r]; bestk[g][r] = code; }
            }
        }
    }

    // ---- reduce across the 16 code-lanes of each row group ----
    #pragma unroll
    for (int off = 1; off < 16; off <<= 1) {
        #pragma unroll
        for (int g = 0; g < 4; ++g) {
            #pragma unroll
            for (int r = 0; r < 4; ++r) {
                const float ov = __shfl_xor(bestv[g][r], off, 64);
                const int   oi = __shfl_xor(bestk[g][r], off, 64);
                if (ov > bestv[g][r] || (ov == bestv[g][r] && oi < bestk[g][r])) {
                    bestv[g][r] = ov; bestk[g][r] = oi;
                }
            }
        }
    }
    if (n16 == 0) {
        #pragma unroll
        for (int g = 0; g < 4; ++g)
            #pragma unroll
            for (int r = 0; r < 4; ++r)
                s_bk[wv * 64 + g * 16 + quad * 4 + r] = bestk[g][r];
    }
    __syncthreads();   // publishes s_bk AND drains the zero stores

    // ---- ones + histogram (ordered after zeros by the barrier) ----
    {
        const int bk = s_bk[tid];
        atomicAdd((unsigned int*)ws + 1024 + bk, 1u);
        encrow0[(size_t)tid * 1024 + bk] = 1.0f;
    }

    // ---- quant + loss from LDS bf16 winner rows (no global loads) ----
    float lsum = 0.f;
    #pragma unroll
    for (int g = 0; g < 4; ++g) {
        const int p  = wv * 64 + g * 16 + n16;
        const int bk = s_bk[p];
        const int ch = (bk >> 4) * 2;
        const int fl = quad * 16 + (bk & 15);
        const S8 w0 = {frag_lds[ch * 64 + fl]};
        const S8 w1 = {frag_lds[(ch + 1) * 64 + fl]};
        float* qbase = out + Q_OFF + (size_t)b * CHW + hw0 + p;
        #pragma unroll
        for (int j = 0; j < 8; ++j) {
            const int d = quad * 8 + j;
            const float q0 = bf2f(w0.u[j]);
            const float q1 = bf2f(w1.u[j]);
            const float d0 = q0 - qx[g][j];
            const float d1 = q1 - qx[g][j + 8];
            lsum = fmaf(d0, d0, lsum);
            lsum = fmaf(d1, d1, lsum);
            qbase[d * HW]        = qx[g][j] + d0;       // straight-through arithmetic
            qbase[(d + 32) * HW] = qx[g][j + 8] + d1;
        }
    }
    #pragma unroll
    for (int off = 1; off < 64; off <<= 1) lsum += __shfl_xor(lsum, off, 64);
    if (lane == 0) atomicAdd(ws + 2048, lsum);
}

__global__ __launch_bounds__(256) void vq_final(const float* __restrict__ ws,
                                                float* __restrict__ out) {
    __shared__ float red[256];
    const int tid = threadIdx.x;
    const unsigned int* hist = (const unsigned int*)ws + 1024;
    float local = 0.f;
    #pragma unroll
    for (int j = 0; j < 4; ++j) {
        const unsigned int cnt = hist[tid + j * 256];
        const float pr = (float)cnt * (1.0f / 65536.0f);
        local += pr * logf(pr + 1e-10f);
    }
    red[tid] = local;
    __syncthreads();
    for (int off = 128; off > 0; off >>= 1) {
        if (tid < off) red[tid] += red[tid + off];
        __syncthreads();
    }
    if (tid == 0) {
        out[PERP_OFF] = expf(-red[0]);
        out[0] = 1.25f * ws[2048] * (1.0f / 4194304.0f);
    }
}

extern "C" void kernel_launch(void* const* d_in, const int* in_sizes, int n_in,
                              void* d_out, int out_size, void* d_ws, size_t ws_size,
                              hipStream_t stream) {
    const float* in = (const float*)d_in[0];   // (16,64,64,64) fp32 NCHW
    const float* W  = (const float*)d_in[1];   // (1024,64) fp32
    float* out = (float*)d_out;                // [loss | quant(4194304) | perp | enc(67108864)]
    float* ws  = (float*)d_ws;

    vq_prep<<<32, 256, 0, stream>>>(W, ws);
    vq_main<<<NPTS / 256, 256, 0, stream>>>(in, W, out, ws);
    vq_final<<<1, 256, 0, stream>>>(ws, out);
}